// Round 13
// baseline (212.287 us; speedup 1.0000x reference)
//
#include <hip/hip_runtime.h>

#define N0        200000
#define N1        25000
#define N2        5000
#define FANOUT    16
#define IN_FEATS  500
#define NH        128
#define NC        47
#define K_PAD     512
#define TILE_R    16                    // rows per kA tile
#define NTILES    (N0 / TILE_R)         // 12500
#define GRID_A    512                   // 2 blocks/CU (8 waves each)

typedef __attribute__((ext_vector_type(4))) float f32x4;
typedef __attribute__((ext_vector_type(8))) short bf16x8;
typedef __attribute__((ext_vector_type(2))) unsigned int uint2_;
typedef __attribute__((ext_vector_type(4))) unsigned int uint4_;
typedef __attribute__((ext_vector_type(4))) int int4_;

__device__ __forceinline__ unsigned short f2bf(float f) {
    unsigned int u = __builtin_bit_cast(unsigned int, f);
    u += 0x7fffu + ((u >> 16) & 1u);          // RNE
    return (unsigned short)(u >> 16);
}
__device__ __forceinline__ float bfhi(unsigned int u) {
    return __builtin_bit_cast(float, u & 0xffff0000u);
}
__device__ __forceinline__ float bflo(unsigned int u) {
    return __builtin_bit_cast(float, u << 16);
}

// ---------------------------------------------------------------------------
// k0: Wt[c][k] = bf16(W1[k][c]), zero-padded to K_PAD.
// ---------------------------------------------------------------------------
__global__ __launch_bounds__(256) void k0_transpose(
    const float* __restrict__ W1, unsigned short* __restrict__ Wt)
{
    __shared__ unsigned short sm[64][NH];
    const int t = threadIdx.x;
    const int kbase = blockIdx.x * 64;

    for (int r = t >> 7; r < 64; r += 2) {
        const int k = kbase + r;
        const int c = t & (NH - 1);
        sm[r][c] = f2bf(k < IN_FEATS ? W1[(size_t)k * NH + c] : 0.f);
    }
    __syncthreads();

    const int c  = t >> 1;
    const int ko = (t & 1) * 32;
    unsigned short* dst = Wt + (size_t)c * K_PAD + kbase + ko;
    #pragma unroll
    for (int i = 0; i < 32; i += 8) {
        bf16x8 v;
        #pragma unroll
        for (int e = 0; e < 8; ++e) v[e] = (short)sm[ko + i + e][c];
        *(bf16x8*)(dst + i) = v;
    }
}

// ---------------------------------------------------------------------------
// kA v6 (R10 form, reverted): dense GEMM H0 = features @ W1, B in REGISTERS,
// double-buffered A tile, direct scalar epilogue stores. Measured ~91 us.
// ---------------------------------------------------------------------------
__global__ __launch_bounds__(512, 4) void kA_gemm(
    const float* __restrict__ features,       // [N0, IN_FEATS]
    const unsigned short* __restrict__ Wt,    // [NH, K_PAD] bf16
    unsigned short* __restrict__ H0)          // [N0, NH] bf16
{
    __shared__ unsigned short A[2][TILE_R * K_PAD];   // 2 x 16 KB, swizzled rows

    const int tid  = threadIdx.x;
    const int lane = tid & 63;
    const int wv   = tid >> 6;                // 0..7 (16-col group)
    const int l15  = lane & 15;
    const int lq   = lane >> 4;               // 0..3

    // preload this wave's B-fragments (cols wv*16+l15, one-time)
    bf16x8 bfrag[16];
    {
        const unsigned short* bp = Wt + (size_t)(wv * 16 + l15) * K_PAD + lq * 8;
        #pragma unroll
        for (int kk = 0; kk < 16; ++kk)
            bfrag[kk] = *(const bf16x8*)(bp + kk * 32);
    }

    // zero the K-pad region (k in [500,512)) of both buffers, once
    if (tid < 96) {
        const int b  = tid / 48, rem = tid % 48;
        const int r  = rem / 3,  j   = rem % 3;
        const int k4 = 500 + j * 4;
        uint2_ z = {0u, 0u};
        *(uint2_*)((char*)&A[b][0] + r * 1024 + ((k4 * 2) ^ ((r & 7) << 4))) = z;
    }

    f32x4 ld[4];
    int cur = 0;
    int t = blockIdx.x;

    // prologue: stage tile t into buffer 0
    {
        const f32x4* slab = (const f32x4*)(features + (size_t)t * TILE_R * IN_FEATS);
        #pragma unroll
        for (int i = 0; i < 3; ++i) ld[i] = __builtin_nontemporal_load(slab + tid + 512 * i);
        if (tid < 464) ld[3] = __builtin_nontemporal_load(slab + tid + 1536);
        #pragma unroll
        for (int i = 0; i < 4; ++i) {
            if (i < 3 || tid < 464) {
                const int c  = tid + 512 * i;          // chunk in [0,2000)
                const int r  = c / 125;                // row 0..15
                const int k4 = (c - r * 125) * 4;      // elem 0..496
                uint2_ w;
                w.x = (unsigned int)f2bf(ld[i].x) | ((unsigned int)f2bf(ld[i].y) << 16);
                w.y = (unsigned int)f2bf(ld[i].z) | ((unsigned int)f2bf(ld[i].w) << 16);
                *(uint2_*)((char*)&A[0][0] + r * 1024 + ((k4 * 2) ^ ((r & 7) << 4))) = w;
            }
        }
    }
    __syncthreads();

    // main pipelined loop
    while (t < NTILES) {
        const int tn = t + GRID_A;

        // (1) issue next tile's loads
        if (tn < NTILES) {
            const f32x4* slab = (const f32x4*)(features + (size_t)tn * TILE_R * IN_FEATS);
            #pragma unroll
            for (int i = 0; i < 3; ++i) ld[i] = __builtin_nontemporal_load(slab + tid + 512 * i);
            if (tid < 464) ld[3] = __builtin_nontemporal_load(slab + tid + 1536);
        }

        // (2) compute current tile: wave wv -> 16 rows x 16 cols, B in regs
        f32x4 acc = (f32x4){0.f, 0.f, 0.f, 0.f};
        const char* base = (const char*)&A[cur][0];
        const int abase = l15 * 1024;
        const int sw    = (l15 & 7) << 4;

        #pragma unroll
        for (int kk = 0; kk < 16; ++kk) {
            const int ke = kk * 32 + lq * 8;
            bf16x8 a = *(const bf16x8*)(base + abase + ((ke * 2) ^ sw));
            acc = __builtin_amdgcn_mfma_f32_16x16x32_bf16(a, bfrag[kk], acc, 0, 0, 0);
        }

        // epilogue: H0 bf16 (col = wv*16+l15, rows lq*4+rr)
        const int rowb = t * TILE_R;
        const int col  = wv * 16 + l15;
        #pragma unroll
        for (int rr = 0; rr < 4; ++rr) {
            H0[(size_t)(rowb + lq * 4 + rr) * NH + col] = f2bf(acc[rr]);
        }

        // (3) write next tile into the other buffer
        if (tn < NTILES) {
            char* nb = (char*)&A[cur ^ 1][0];
            #pragma unroll
            for (int i = 0; i < 4; ++i) {
                if (i < 3 || tid < 464) {
                    const int c  = tid + 512 * i;
                    const int r  = c / 125;
                    const int k4 = (c - r * 125) * 4;
                    uint2_ w;
                    w.x = (unsigned int)f2bf(ld[i].x) | ((unsigned int)f2bf(ld[i].y) << 16);
                    w.y = (unsigned int)f2bf(ld[i].z) | ((unsigned int)f2bf(ld[i].w) << 16);
                    *(uint2_*)(nb + r * 1024 + ((k4 * 2) ^ ((r & 7) << 4))) = w;
                }
            }
        }

        __syncthreads();
        cur ^= 1;
        t = tn;
    }
}

// ---------------------------------------------------------------------------
// kB v3: h1cat[i] = [m + b1, relu(m + b1)], m = mean_j H0[src0[i,j]].
// One row per wave; lane = (c16, jq); butterfly over jq. (unchanged)
// ---------------------------------------------------------------------------
__global__ __launch_bounds__(256, 8) void kB_gather(
    const unsigned short* __restrict__ H0,    // [N0, NH] bf16
    const int*   __restrict__ src0,           // [N1, FANOUT]
    const float* __restrict__ b1,             // [NH]
    unsigned short* __restrict__ h1cat)       // [N1, 2*NH] bf16
{
    const int lane = threadIdx.x & 63;
    const int wv   = threadIdx.x >> 6;        // 0..3
    const int row  = blockIdx.x * 4 + wv;     // N1 = 6250*4 exact
    const int c16  = lane >> 2;               // 0..15: 8-col chunk
    const int jq   = lane & 3;                // neighbor phase

    int4_ nb4 = *(const int4_*)(src0 + row * FANOUT + jq * 4);

    const size_t c8 = (size_t)c16 * 8;
    float acc[8] = {0.f,0.f,0.f,0.f,0.f,0.f,0.f,0.f};

    uint4_ v0 = *(const uint4_*)(H0 + (size_t)nb4.x * NH + c8);
    uint4_ v1 = *(const uint4_*)(H0 + (size_t)nb4.y * NH + c8);
    uint4_ v2 = *(const uint4_*)(H0 + (size_t)nb4.z * NH + c8);
    uint4_ v3 = *(const uint4_*)(H0 + (size_t)nb4.w * NH + c8);

    acc[0] += bflo(v0.x); acc[1] += bfhi(v0.x); acc[2] += bflo(v0.y); acc[3] += bfhi(v0.y);
    acc[4] += bflo(v0.z); acc[5] += bfhi(v0.z); acc[6] += bflo(v0.w); acc[7] += bfhi(v0.w);
    acc[0] += bflo(v1.x); acc[1] += bfhi(v1.x); acc[2] += bflo(v1.y); acc[3] += bfhi(v1.y);
    acc[4] += bflo(v1.z); acc[5] += bfhi(v1.z); acc[6] += bflo(v1.w); acc[7] += bfhi(v1.w);
    acc[0] += bflo(v2.x); acc[1] += bfhi(v2.x); acc[2] += bflo(v2.y); acc[3] += bfhi(v2.y);
    acc[4] += bflo(v2.z); acc[5] += bfhi(v2.z); acc[6] += bflo(v2.w); acc[7] += bfhi(v2.w);
    acc[0] += bflo(v3.x); acc[1] += bfhi(v3.x); acc[2] += bflo(v3.y); acc[3] += bfhi(v3.y);
    acc[4] += bflo(v3.z); acc[5] += bfhi(v3.z); acc[6] += bflo(v3.w); acc[7] += bfhi(v3.w);

    #pragma unroll
    for (int e = 0; e < 8; ++e) {
        float a = acc[e];
        a += __shfl_xor(a, 1);
        a += __shfl_xor(a, 2);
        acc[e] = a;
    }

    f32x4 b_lo = *(const f32x4*)(b1 + c8);
    f32x4 b_hi = *(const f32x4*)(b1 + c8 + 4);
    float h[8];
    h[0] = acc[0]*0.0625f + b_lo.x; h[1] = acc[1]*0.0625f + b_lo.y;
    h[2] = acc[2]*0.0625f + b_lo.z; h[3] = acc[3]*0.0625f + b_lo.w;
    h[4] = acc[4]*0.0625f + b_hi.x; h[5] = acc[5]*0.0625f + b_hi.y;
    h[6] = acc[6]*0.0625f + b_hi.z; h[7] = acc[7]*0.0625f + b_hi.w;

    unsigned short* dst = h1cat + (size_t)row * 256;
    if (jq == 0) {                // h half
        uint4_ w;
        w.x = (unsigned int)f2bf(h[0]) | ((unsigned int)f2bf(h[1]) << 16);
        w.y = (unsigned int)f2bf(h[2]) | ((unsigned int)f2bf(h[3]) << 16);
        w.z = (unsigned int)f2bf(h[4]) | ((unsigned int)f2bf(h[5]) << 16);
        w.w = (unsigned int)f2bf(h[6]) | ((unsigned int)f2bf(h[7]) << 16);
        *(uint4_*)(dst + c8) = w;
    } else if (jq == 1) {         // relu half
        uint4_ w;
        w.x = (unsigned int)f2bf(h[0]>0.f?h[0]:0.f) | ((unsigned int)f2bf(h[1]>0.f?h[1]:0.f) << 16);
        w.y = (unsigned int)f2bf(h[2]>0.f?h[2]:0.f) | ((unsigned int)f2bf(h[3]>0.f?h[3]:0.f) << 16);
        w.z = (unsigned int)f2bf(h[4]>0.f?h[4]:0.f) | ((unsigned int)f2bf(h[5]>0.f?h[5]:0.f) << 16);
        w.w = (unsigned int)f2bf(h[6]>0.f?h[6]:0.f) | ((unsigned int)f2bf(h[7]>0.f?h[7]:0.f) << 16);
        *(uint4_*)(dst + NH + c8) = w;
    }
}

// ---------------------------------------------------------------------------
// kG: G = h1cat @ W2 + b2 over ALL N1 rows (dense streaming, tiny GEMM).
// ---------------------------------------------------------------------------
__global__ __launch_bounds__(256) void kG_gemm(
    const unsigned short* __restrict__ h1cat, // [N1, 256] bf16
    const float* __restrict__ W2,             // [256, NC]
    const float* __restrict__ b2,             // [NC]
    float*       __restrict__ G)              // [N1, NC] f32
{
    __shared__ float sm[8][256];

    const int tid  = threadIdx.x;
    const int row0 = blockIdx.x * 8;
    const int r    = tid >> 5;
    const int s    = tid & 31;

    // stage 8 rows (coalesced 16B loads)
    {
        uint4_ v = *(const uint4_*)(h1cat + (size_t)(row0 + r) * 256 + s * 8);
        float* d = &sm[r][s * 8];
        d[0]=bflo(v.x); d[1]=bfhi(v.x); d[2]=bflo(v.y); d[3]=bfhi(v.y);
        d[4]=bflo(v.z); d[5]=bfhi(v.z); d[6]=bflo(v.w); d[7]=bfhi(v.w);
    }
    __syncthreads();

    const int c0 = s, c1 = s + 32;
    float o0 = b2[c0];
    float o1 = (c1 < NC) ? b2[c1] : 0.f;
    for (int k = 0; k < 256; k += 4) {
        f32x4 mv = *(const f32x4*)&sm[r][k];
        #pragma unroll
        for (int e = 0; e < 4; ++e) {
            const float* wrow = W2 + (size_t)(k + e) * NC;
            o0 += mv[e] * wrow[c0];
            if (c1 < NC) o1 += mv[e] * wrow[c1];
        }
    }
    G[(size_t)(row0 + r) * NC + c0] = o0;
    if (c1 < NC) G[(size_t)(row0 + r) * NC + c1] = o1;
}

// ---------------------------------------------------------------------------
// k2 v2: out[i] = mean_j G[src1[i,j]]  (b2 already folded into G).
// ---------------------------------------------------------------------------
__global__ __launch_bounds__(256, 8) void k2_gather(
    const float* __restrict__ G,              // [N1, NC] f32
    const int*   __restrict__ src1,           // [N2, FANOUT]
    float*       __restrict__ out)            // [N2, NC] f32
{
    const int lane = threadIdx.x & 63;
    const int wv   = threadIdx.x >> 6;
    const int row  = blockIdx.x * 4 + wv;     // N2 = 1250*4 exact
    const int rb   = row * FANOUT;

    if (lane < NC) {
        float acc = 0.f;
        #pragma unroll
        for (int j = 0; j < FANOUT; ++j) {
            const int nb = src1[rb + j];       // wave-uniform -> scalar load
            acc += G[(size_t)nb * NC + lane];
        }
        out[(size_t)row * NC + lane] = acc * 0.0625f;
    }
}

extern "C" void kernel_launch(void* const* d_in, const int* in_sizes, int n_in,
                              void* d_out, int out_size, void* d_ws, size_t ws_size,
                              hipStream_t stream)
{
    const float* features = (const float*)d_in[0];
    const int*   src0     = (const int*)  d_in[1];
    const int*   src1     = (const int*)  d_in[2];
    const float* W1       = (const float*)d_in[3];
    const float* b1       = (const float*)d_in[4];
    const float* W2       = (const float*)d_in[5];
    const float* b2       = (const float*)d_in[6];
    float*       out      = (float*)d_out;

    unsigned short* Wt    = (unsigned short*)d_ws;        // [NH][K_PAD]  = 128 KB
    unsigned short* H0    = Wt + (size_t)NH * K_PAD;      // [N0][NH] bf16 = 51.2 MB
    unsigned short* h1cat = H0 + (size_t)N0 * NH;         // [N1][256] bf16 = 12.8 MB
    float*          G     = (float*)(h1cat + (size_t)N1 * 256);  // [N1][NC] f32 = 4.7 MB

    hipLaunchKernelGGL(k0_transpose, dim3(K_PAD / 64), dim3(256), 0, stream, W1, Wt);
    hipLaunchKernelGGL(kA_gemm,   dim3(GRID_A),        dim3(512), 0, stream, features, Wt, H0);
    hipLaunchKernelGGL(kB_gather, dim3(N1 / 4),        dim3(256), 0, stream, H0, src0, b1, h1cat);
    hipLaunchKernelGGL(kG_gemm,   dim3(N1 / 8),        dim3(256), 0, stream, h1cat, W2, b2, G);
    hipLaunchKernelGGL(k2_gather, dim3(N2 / 4),        dim3(256), 0, stream, G, src1, out);
}

// Round 14
// 182.131 us; speedup vs baseline: 1.1656x; 1.1656x over previous
//
#include <hip/hip_runtime.h>

#define N0        200000
#define N1        25000
#define N2        5000
#define FANOUT    16
#define IN_FEATS  500
#define NH        128
#define NC        47
#define K_PAD     512
#define TILE_R    16                    // rows per kA tile
#define NTILES    (N0 / TILE_R)         // 12500
#define GRID_A    512                   // 2 blocks/CU (8 waves each)

typedef __attribute__((ext_vector_type(4))) float f32x4;
typedef __attribute__((ext_vector_type(8))) short bf16x8;
typedef __attribute__((ext_vector_type(2))) unsigned int uint2_;
typedef __attribute__((ext_vector_type(4))) unsigned int uint4_;
typedef __attribute__((ext_vector_type(4))) int int4_;

__device__ __forceinline__ unsigned short f2bf(float f) {
    unsigned int u = __builtin_bit_cast(unsigned int, f);
    u += 0x7fffu + ((u >> 16) & 1u);          // RNE
    return (unsigned short)(u >> 16);
}
__device__ __forceinline__ float bfhi(unsigned int u) {
    return __builtin_bit_cast(float, u & 0xffff0000u);
}
__device__ __forceinline__ float bflo(unsigned int u) {
    return __builtin_bit_cast(float, u << 16);
}

// ---------------------------------------------------------------------------
// k0: Wt[c][k] = bf16(W1[k][c]), zero-padded to K_PAD.
// ---------------------------------------------------------------------------
__global__ __launch_bounds__(256) void k0_transpose(
    const float* __restrict__ W1, unsigned short* __restrict__ Wt)
{
    __shared__ unsigned short sm[64][NH];
    const int t = threadIdx.x;
    const int kbase = blockIdx.x * 64;

    for (int r = t >> 7; r < 64; r += 2) {
        const int k = kbase + r;
        const int c = t & (NH - 1);
        sm[r][c] = f2bf(k < IN_FEATS ? W1[(size_t)k * NH + c] : 0.f);
    }
    __syncthreads();

    const int c  = t >> 1;
    const int ko = (t & 1) * 32;
    unsigned short* dst = Wt + (size_t)c * K_PAD + kbase + ko;
    #pragma unroll
    for (int i = 0; i < 32; i += 8) {
        bf16x8 v;
        #pragma unroll
        for (int e = 0; e < 8; ++e) v[e] = (short)sm[ko + i + e][c];
        *(bf16x8*)(dst + i) = v;
    }
}

// ---------------------------------------------------------------------------
// kA v6 (R10 form, best measured ~91 us): dense GEMM H0 = features @ W1,
// B in REGISTERS, double-buffered A tile, direct epilogue stores.
// ---------------------------------------------------------------------------
__global__ __launch_bounds__(512, 4) void kA_gemm(
    const float* __restrict__ features,       // [N0, IN_FEATS]
    const unsigned short* __restrict__ Wt,    // [NH, K_PAD] bf16
    unsigned short* __restrict__ H0)          // [N0, NH] bf16
{
    __shared__ unsigned short A[2][TILE_R * K_PAD];   // 2 x 16 KB, swizzled rows

    const int tid  = threadIdx.x;
    const int lane = tid & 63;
    const int wv   = tid >> 6;                // 0..7 (16-col group)
    const int l15  = lane & 15;
    const int lq   = lane >> 4;               // 0..3

    // preload this wave's B-fragments (cols wv*16+l15, one-time)
    bf16x8 bfrag[16];
    {
        const unsigned short* bp = Wt + (size_t)(wv * 16 + l15) * K_PAD + lq * 8;
        #pragma unroll
        for (int kk = 0; kk < 16; ++kk)
            bfrag[kk] = *(const bf16x8*)(bp + kk * 32);
    }

    // zero the K-pad region (k in [500,512)) of both buffers, once
    if (tid < 96) {
        const int b  = tid / 48, rem = tid % 48;
        const int r  = rem / 3,  j   = rem % 3;
        const int k4 = 500 + j * 4;
        uint2_ z = {0u, 0u};
        *(uint2_*)((char*)&A[b][0] + r * 1024 + ((k4 * 2) ^ ((r & 7) << 4))) = z;
    }

    f32x4 ld[4];
    int cur = 0;
    int t = blockIdx.x;

    // prologue: stage tile t into buffer 0
    {
        const f32x4* slab = (const f32x4*)(features + (size_t)t * TILE_R * IN_FEATS);
        #pragma unroll
        for (int i = 0; i < 3; ++i) ld[i] = __builtin_nontemporal_load(slab + tid + 512 * i);
        if (tid < 464) ld[3] = __builtin_nontemporal_load(slab + tid + 1536);
        #pragma unroll
        for (int i = 0; i < 4; ++i) {
            if (i < 3 || tid < 464) {
                const int c  = tid + 512 * i;          // chunk in [0,2000)
                const int r  = c / 125;                // row 0..15
                const int k4 = (c - r * 125) * 4;      // elem 0..496
                uint2_ w;
                w.x = (unsigned int)f2bf(ld[i].x) | ((unsigned int)f2bf(ld[i].y) << 16);
                w.y = (unsigned int)f2bf(ld[i].z) | ((unsigned int)f2bf(ld[i].w) << 16);
                *(uint2_*)((char*)&A[0][0] + r * 1024 + ((k4 * 2) ^ ((r & 7) << 4))) = w;
            }
        }
    }
    __syncthreads();

    // main pipelined loop
    while (t < NTILES) {
        const int tn = t + GRID_A;

        // (1) issue next tile's loads
        if (tn < NTILES) {
            const f32x4* slab = (const f32x4*)(features + (size_t)tn * TILE_R * IN_FEATS);
            #pragma unroll
            for (int i = 0; i < 3; ++i) ld[i] = __builtin_nontemporal_load(slab + tid + 512 * i);
            if (tid < 464) ld[3] = __builtin_nontemporal_load(slab + tid + 1536);
        }

        // (2) compute current tile: wave wv -> 16 rows x 16 cols, B in regs
        f32x4 acc = (f32x4){0.f, 0.f, 0.f, 0.f};
        const char* base = (const char*)&A[cur][0];
        const int abase = l15 * 1024;
        const int sw    = (l15 & 7) << 4;

        #pragma unroll
        for (int kk = 0; kk < 16; ++kk) {
            const int ke = kk * 32 + lq * 8;
            bf16x8 a = *(const bf16x8*)(base + abase + ((ke * 2) ^ sw));
            acc = __builtin_amdgcn_mfma_f32_16x16x32_bf16(a, bfrag[kk], acc, 0, 0, 0);
        }

        // epilogue: H0 bf16 (col = wv*16+l15, rows lq*4+rr)
        const int rowb = t * TILE_R;
        const int col  = wv * 16 + l15;
        #pragma unroll
        for (int rr = 0; rr < 4; ++rr) {
            H0[(size_t)(rowb + lq * 4 + rr) * NH + col] = f2bf(acc[rr]);
        }

        // (3) write next tile into the other buffer
        if (tn < NTILES) {
            char* nb = (char*)&A[cur ^ 1][0];
            #pragma unroll
            for (int i = 0; i < 4; ++i) {
                if (i < 3 || tid < 464) {
                    const int c  = tid + 512 * i;
                    const int r  = c / 125;
                    const int k4 = (c - r * 125) * 4;
                    uint2_ w;
                    w.x = (unsigned int)f2bf(ld[i].x) | ((unsigned int)f2bf(ld[i].y) << 16);
                    w.y = (unsigned int)f2bf(ld[i].z) | ((unsigned int)f2bf(ld[i].w) << 16);
                    *(uint2_*)(nb + r * 1024 + ((k4 * 2) ^ ((r & 7) << 4))) = w;
                }
            }
        }

        __syncthreads();
        cur ^= 1;
        t = tn;
    }
}

// ---------------------------------------------------------------------------
// kB v3: h1cat[i] = [m + b1, relu(m + b1)], m = mean_j H0[src0[i,j]].
// One row per wave; lane = (c16, jq); butterfly over jq.
// ---------------------------------------------------------------------------
__global__ __launch_bounds__(256, 8) void kB_gather(
    const unsigned short* __restrict__ H0,    // [N0, NH] bf16
    const int*   __restrict__ src0,           // [N1, FANOUT]
    const float* __restrict__ b1,             // [NH]
    unsigned short* __restrict__ h1cat)       // [N1, 2*NH] bf16
{
    const int lane = threadIdx.x & 63;
    const int wv   = threadIdx.x >> 6;        // 0..3
    const int row  = blockIdx.x * 4 + wv;     // N1 = 6250*4 exact
    const int c16  = lane >> 2;               // 0..15: 8-col chunk
    const int jq   = lane & 3;                // neighbor phase

    int4_ nb4 = *(const int4_*)(src0 + row * FANOUT + jq * 4);

    const size_t c8 = (size_t)c16 * 8;
    float acc[8] = {0.f,0.f,0.f,0.f,0.f,0.f,0.f,0.f};

    uint4_ v0 = *(const uint4_*)(H0 + (size_t)nb4.x * NH + c8);
    uint4_ v1 = *(const uint4_*)(H0 + (size_t)nb4.y * NH + c8);
    uint4_ v2 = *(const uint4_*)(H0 + (size_t)nb4.z * NH + c8);
    uint4_ v3 = *(const uint4_*)(H0 + (size_t)nb4.w * NH + c8);

    acc[0] += bflo(v0.x); acc[1] += bfhi(v0.x); acc[2] += bflo(v0.y); acc[3] += bfhi(v0.y);
    acc[4] += bflo(v0.z); acc[5] += bfhi(v0.z); acc[6] += bflo(v0.w); acc[7] += bfhi(v0.w);
    acc[0] += bflo(v1.x); acc[1] += bfhi(v1.x); acc[2] += bflo(v1.y); acc[3] += bfhi(v1.y);
    acc[4] += bflo(v1.z); acc[5] += bfhi(v1.z); acc[6] += bflo(v1.w); acc[7] += bfhi(v1.w);
    acc[0] += bflo(v2.x); acc[1] += bfhi(v2.x); acc[2] += bflo(v2.y); acc[3] += bfhi(v2.y);
    acc[4] += bflo(v2.z); acc[5] += bfhi(v2.z); acc[6] += bflo(v2.w); acc[7] += bfhi(v2.w);
    acc[0] += bflo(v3.x); acc[1] += bfhi(v3.x); acc[2] += bflo(v3.y); acc[3] += bfhi(v3.y);
    acc[4] += bflo(v3.z); acc[5] += bfhi(v3.z); acc[6] += bflo(v3.w); acc[7] += bfhi(v3.w);

    #pragma unroll
    for (int e = 0; e < 8; ++e) {
        float a = acc[e];
        a += __shfl_xor(a, 1);
        a += __shfl_xor(a, 2);
        acc[e] = a;
    }

    f32x4 b_lo = *(const f32x4*)(b1 + c8);
    f32x4 b_hi = *(const f32x4*)(b1 + c8 + 4);
    float h[8];
    h[0] = acc[0]*0.0625f + b_lo.x; h[1] = acc[1]*0.0625f + b_lo.y;
    h[2] = acc[2]*0.0625f + b_lo.z; h[3] = acc[3]*0.0625f + b_lo.w;
    h[4] = acc[4]*0.0625f + b_hi.x; h[5] = acc[5]*0.0625f + b_hi.y;
    h[6] = acc[6]*0.0625f + b_hi.z; h[7] = acc[7]*0.0625f + b_hi.w;

    unsigned short* dst = h1cat + (size_t)row * 256;
    if (jq == 0) {                // h half
        uint4_ w;
        w.x = (unsigned int)f2bf(h[0]) | ((unsigned int)f2bf(h[1]) << 16);
        w.y = (unsigned int)f2bf(h[2]) | ((unsigned int)f2bf(h[3]) << 16);
        w.z = (unsigned int)f2bf(h[4]) | ((unsigned int)f2bf(h[5]) << 16);
        w.w = (unsigned int)f2bf(h[6]) | ((unsigned int)f2bf(h[7]) << 16);
        *(uint4_*)(dst + c8) = w;
    } else if (jq == 1) {         // relu half
        uint4_ w;
        w.x = (unsigned int)f2bf(h[0]>0.f?h[0]:0.f) | ((unsigned int)f2bf(h[1]>0.f?h[1]:0.f) << 16);
        w.y = (unsigned int)f2bf(h[2]>0.f?h[2]:0.f) | ((unsigned int)f2bf(h[3]>0.f?h[3]:0.f) << 16);
        w.z = (unsigned int)f2bf(h[4]>0.f?h[4]:0.f) | ((unsigned int)f2bf(h[5]>0.f?h[5]:0.f) << 16);
        w.w = (unsigned int)f2bf(h[6]>0.f?h[6]:0.f) | ((unsigned int)f2bf(h[7]>0.f?h[7]:0.f) << 16);
        *(uint4_*)(dst + NH + c8) = w;
    }
}

// ---------------------------------------------------------------------------
// k2: gather-mean over bf16 h1cat + f32 GEMM [8x256]@[256x47] + bias.
// (R11-validated fused form)
// ---------------------------------------------------------------------------
__global__ __launch_bounds__(256) void k2_fused(
    const unsigned short* __restrict__ h1cat, // [N1, 256] bf16
    const int*   __restrict__ src1,           // [N2, FANOUT]
    const float* __restrict__ W2,             // [256, NC]
    const float* __restrict__ b2,             // [NC]
    float*       __restrict__ out)            // [N2, NC]
{
    __shared__ float sm[8][256];

    const int tid = threadIdx.x;
    const int r   = tid >> 5;
    const int s   = tid & 31;
    const int row = blockIdx.x * 8 + r;

    float acc[8] = {0.f,0.f,0.f,0.f,0.f,0.f,0.f,0.f};
    #pragma unroll
    for (int j = 0; j < FANOUT; ++j) {
        const int nb = src1[row * FANOUT + j];
        uint4_ v = *(const uint4_*)(h1cat + (size_t)nb * 256 + s * 8);
        acc[0] += bflo(v.x); acc[1] += bfhi(v.x);
        acc[2] += bflo(v.y); acc[3] += bfhi(v.y);
        acc[4] += bflo(v.z); acc[5] += bfhi(v.z);
        acc[6] += bflo(v.w); acc[7] += bfhi(v.w);
    }
    #pragma unroll
    for (int e = 0; e < 8; ++e) sm[r][s * 8 + e] = acc[e] * 0.0625f;
    __syncthreads();

    const int c0 = s, c1 = s + 32;
    float o0 = b2[c0];
    float o1 = (c1 < NC) ? b2[c1] : 0.f;
    for (int k = 0; k < 256; k += 4) {
        f32x4 mv = *(const f32x4*)&sm[r][k];
        #pragma unroll
        for (int e = 0; e < 4; ++e) {
            const float* wrow = W2 + (size_t)(k + e) * NC;
            o0 += mv[e] * wrow[c0];
            if (c1 < NC) o1 += mv[e] * wrow[c1];
        }
    }
    out[(size_t)row * NC + c0] = o0;
    if (c1 < NC) out[(size_t)row * NC + c1] = o1;
}

extern "C" void kernel_launch(void* const* d_in, const int* in_sizes, int n_in,
                              void* d_out, int out_size, void* d_ws, size_t ws_size,
                              hipStream_t stream)
{
    const float* features = (const float*)d_in[0];
    const int*   src0     = (const int*)  d_in[1];
    const int*   src1     = (const int*)  d_in[2];
    const float* W1       = (const float*)d_in[3];
    const float* b1       = (const float*)d_in[4];
    const float* W2       = (const float*)d_in[5];
    const float* b2       = (const float*)d_in[6];
    float*       out      = (float*)d_out;

    unsigned short* Wt    = (unsigned short*)d_ws;        // [NH][K_PAD]  = 128 KB
    unsigned short* H0    = Wt + (size_t)NH * K_PAD;      // [N0][NH] bf16 = 51.2 MB
    unsigned short* h1cat = H0 + (size_t)N0 * NH;         // [N1][256] bf16 = 12.8 MB

    hipLaunchKernelGGL(k0_transpose, dim3(K_PAD / 64), dim3(256), 0, stream, W1, Wt);
    hipLaunchKernelGGL(kA_gemm,   dim3(GRID_A),        dim3(512), 0, stream, features, Wt, H0);
    hipLaunchKernelGGL(kB_gather, dim3(N1 / 4),        dim3(256), 0, stream, H0, src0, b1, h1cat);
    hipLaunchKernelGGL(k2_fused,  dim3(N2 / 8),        dim3(256), 0, stream, h1cat, src1, W2, b2, out);
}

// Round 15
// 179.299 us; speedup vs baseline: 1.1840x; 1.0158x over previous
//
#include <hip/hip_runtime.h>

#define N0        200000
#define N1        25000
#define N2        5000
#define FANOUT    16
#define IN_FEATS  500
#define NH        128
#define NC        47
#define K_PAD     512
#define TILE_R    16                    // rows per kA tile
#define NTILES    (N0 / TILE_R)         // 12500
#define GRID_A    512                   // 2 blocks/CU (8 waves each)

typedef __attribute__((ext_vector_type(4))) float f32x4;
typedef __attribute__((ext_vector_type(8))) short bf16x8;
typedef __attribute__((ext_vector_type(2))) unsigned int uint2_;
typedef __attribute__((ext_vector_type(4))) unsigned int uint4_;
typedef __attribute__((ext_vector_type(4))) int int4_;

__device__ __forceinline__ unsigned short f2bf(float f) {
    unsigned int u = __builtin_bit_cast(unsigned int, f);
    u += 0x7fffu + ((u >> 16) & 1u);          // RNE
    return (unsigned short)(u >> 16);
}
__device__ __forceinline__ float bfhi(unsigned int u) {
    return __builtin_bit_cast(float, u & 0xffff0000u);
}
__device__ __forceinline__ float bflo(unsigned int u) {
    return __builtin_bit_cast(float, u << 16);
}

// ---------------------------------------------------------------------------
// k0: Wt[c][k] = bf16(W1[k][c]), zero-padded to K_PAD.
// ---------------------------------------------------------------------------
__global__ __launch_bounds__(256) void k0_transpose(
    const float* __restrict__ W1, unsigned short* __restrict__ Wt)
{
    __shared__ unsigned short sm[64][NH];
    const int t = threadIdx.x;
    const int kbase = blockIdx.x * 64;

    for (int r = t >> 7; r < 64; r += 2) {
        const int k = kbase + r;
        const int c = t & (NH - 1);
        sm[r][c] = f2bf(k < IN_FEATS ? W1[(size_t)k * NH + c] : 0.f);
    }
    __syncthreads();

    const int c  = t >> 1;
    const int ko = (t & 1) * 32;
    unsigned short* dst = Wt + (size_t)c * K_PAD + kbase + ko;
    #pragma unroll
    for (int i = 0; i < 32; i += 8) {
        bf16x8 v;
        #pragma unroll
        for (int e = 0; e < 8; ++e) v[e] = (short)sm[ko + i + e][c];
        *(bf16x8*)(dst + i) = v;
    }
}

// ---------------------------------------------------------------------------
// kA v6 (R10 form, best measured ~91 us): dense GEMM H0 = features @ W1,
// B in REGISTERS, double-buffered A tile, direct epilogue stores.
// ---------------------------------------------------------------------------
__global__ __launch_bounds__(512, 4) void kA_gemm(
    const float* __restrict__ features,       // [N0, IN_FEATS]
    const unsigned short* __restrict__ Wt,    // [NH, K_PAD] bf16
    unsigned short* __restrict__ H0)          // [N0, NH] bf16
{
    __shared__ unsigned short A[2][TILE_R * K_PAD];   // 2 x 16 KB, swizzled rows

    const int tid  = threadIdx.x;
    const int lane = tid & 63;
    const int wv   = tid >> 6;                // 0..7 (16-col group)
    const int l15  = lane & 15;
    const int lq   = lane >> 4;               // 0..3

    // preload this wave's B-fragments (cols wv*16+l15, one-time)
    bf16x8 bfrag[16];
    {
        const unsigned short* bp = Wt + (size_t)(wv * 16 + l15) * K_PAD + lq * 8;
        #pragma unroll
        for (int kk = 0; kk < 16; ++kk)
            bfrag[kk] = *(const bf16x8*)(bp + kk * 32);
    }

    // zero the K-pad region (k in [500,512)) of both buffers, once
    if (tid < 96) {
        const int b  = tid / 48, rem = tid % 48;
        const int r  = rem / 3,  j   = rem % 3;
        const int k4 = 500 + j * 4;
        uint2_ z = {0u, 0u};
        *(uint2_*)((char*)&A[b][0] + r * 1024 + ((k4 * 2) ^ ((r & 7) << 4))) = z;
    }

    f32x4 ld[4];
    int cur = 0;
    int t = blockIdx.x;

    // prologue: stage tile t into buffer 0
    {
        const f32x4* slab = (const f32x4*)(features + (size_t)t * TILE_R * IN_FEATS);
        #pragma unroll
        for (int i = 0; i < 3; ++i) ld[i] = __builtin_nontemporal_load(slab + tid + 512 * i);
        if (tid < 464) ld[3] = __builtin_nontemporal_load(slab + tid + 1536);
        #pragma unroll
        for (int i = 0; i < 4; ++i) {
            if (i < 3 || tid < 464) {
                const int c  = tid + 512 * i;          // chunk in [0,2000)
                const int r  = c / 125;                // row 0..15
                const int k4 = (c - r * 125) * 4;      // elem 0..496
                uint2_ w;
                w.x = (unsigned int)f2bf(ld[i].x) | ((unsigned int)f2bf(ld[i].y) << 16);
                w.y = (unsigned int)f2bf(ld[i].z) | ((unsigned int)f2bf(ld[i].w) << 16);
                *(uint2_*)((char*)&A[0][0] + r * 1024 + ((k4 * 2) ^ ((r & 7) << 4))) = w;
            }
        }
    }
    __syncthreads();

    // main pipelined loop
    while (t < NTILES) {
        const int tn = t + GRID_A;

        // (1) issue next tile's loads
        if (tn < NTILES) {
            const f32x4* slab = (const f32x4*)(features + (size_t)tn * TILE_R * IN_FEATS);
            #pragma unroll
            for (int i = 0; i < 3; ++i) ld[i] = __builtin_nontemporal_load(slab + tid + 512 * i);
            if (tid < 464) ld[3] = __builtin_nontemporal_load(slab + tid + 1536);
        }

        // (2) compute current tile: wave wv -> 16 rows x 16 cols, B in regs
        f32x4 acc = (f32x4){0.f, 0.f, 0.f, 0.f};
        const char* base = (const char*)&A[cur][0];
        const int abase = l15 * 1024;
        const int sw    = (l15 & 7) << 4;

        #pragma unroll
        for (int kk = 0; kk < 16; ++kk) {
            const int ke = kk * 32 + lq * 8;
            bf16x8 a = *(const bf16x8*)(base + abase + ((ke * 2) ^ sw));
            acc = __builtin_amdgcn_mfma_f32_16x16x32_bf16(a, bfrag[kk], acc, 0, 0, 0);
        }

        // epilogue: H0 bf16 (col = wv*16+l15, rows lq*4+rr)
        const int rowb = t * TILE_R;
        const int col  = wv * 16 + l15;
        #pragma unroll
        for (int rr = 0; rr < 4; ++rr) {
            H0[(size_t)(rowb + lq * 4 + rr) * NH + col] = f2bf(acc[rr]);
        }

        // (3) write next tile into the other buffer
        if (tn < NTILES) {
            char* nb = (char*)&A[cur ^ 1][0];
            #pragma unroll
            for (int i = 0; i < 4; ++i) {
                if (i < 3 || tid < 464) {
                    const int c  = tid + 512 * i;
                    const int r  = c / 125;
                    const int k4 = (c - r * 125) * 4;
                    uint2_ w;
                    w.x = (unsigned int)f2bf(ld[i].x) | ((unsigned int)f2bf(ld[i].y) << 16);
                    w.y = (unsigned int)f2bf(ld[i].z) | ((unsigned int)f2bf(ld[i].w) << 16);
                    *(uint2_*)(nb + r * 1024 + ((k4 * 2) ^ ((r & 7) << 4))) = w;
                }
            }
        }

        __syncthreads();
        cur ^= 1;
        t = tn;
    }
}

// ---------------------------------------------------------------------------
// kB v4: H1[i] = mean_j H0[src0[i,j]] + b1   (NO relu half stored —
// k2 derives relu per-neighbor in-register). Row = 128 bf16 = 256 B.
// One row per wave; lane = (c16, jq); butterfly over jq.
// ---------------------------------------------------------------------------
__global__ __launch_bounds__(256, 8) void kB_gather(
    const unsigned short* __restrict__ H0,    // [N0, NH] bf16
    const int*   __restrict__ src0,           // [N1, FANOUT]
    const float* __restrict__ b1,             // [NH]
    unsigned short* __restrict__ H1)          // [N1, NH] bf16
{
    const int lane = threadIdx.x & 63;
    const int wv   = threadIdx.x >> 6;        // 0..3
    const int row  = blockIdx.x * 4 + wv;     // N1 = 6250*4 exact
    const int c16  = lane >> 2;               // 0..15: 8-col chunk
    const int jq   = lane & 3;                // neighbor phase

    int4_ nb4 = *(const int4_*)(src0 + row * FANOUT + jq * 4);

    const size_t c8 = (size_t)c16 * 8;
    float acc[8] = {0.f,0.f,0.f,0.f,0.f,0.f,0.f,0.f};

    uint4_ v0 = *(const uint4_*)(H0 + (size_t)nb4.x * NH + c8);
    uint4_ v1 = *(const uint4_*)(H0 + (size_t)nb4.y * NH + c8);
    uint4_ v2 = *(const uint4_*)(H0 + (size_t)nb4.z * NH + c8);
    uint4_ v3 = *(const uint4_*)(H0 + (size_t)nb4.w * NH + c8);

    acc[0] += bflo(v0.x); acc[1] += bfhi(v0.x); acc[2] += bflo(v0.y); acc[3] += bfhi(v0.y);
    acc[4] += bflo(v0.z); acc[5] += bfhi(v0.z); acc[6] += bflo(v0.w); acc[7] += bfhi(v0.w);
    acc[0] += bflo(v1.x); acc[1] += bfhi(v1.x); acc[2] += bflo(v1.y); acc[3] += bfhi(v1.y);
    acc[4] += bflo(v1.z); acc[5] += bfhi(v1.z); acc[6] += bflo(v1.w); acc[7] += bfhi(v1.w);
    acc[0] += bflo(v2.x); acc[1] += bfhi(v2.x); acc[2] += bflo(v2.y); acc[3] += bfhi(v2.y);
    acc[4] += bflo(v2.z); acc[5] += bfhi(v2.z); acc[6] += bflo(v2.w); acc[7] += bfhi(v2.w);
    acc[0] += bflo(v3.x); acc[1] += bfhi(v3.x); acc[2] += bflo(v3.y); acc[3] += bfhi(v3.y);
    acc[4] += bflo(v3.z); acc[5] += bfhi(v3.z); acc[6] += bflo(v3.w); acc[7] += bfhi(v3.w);

    #pragma unroll
    for (int e = 0; e < 8; ++e) {
        float a = acc[e];
        a += __shfl_xor(a, 1);
        a += __shfl_xor(a, 2);
        acc[e] = a;
    }

    if (jq == 0) {
        f32x4 b_lo = *(const f32x4*)(b1 + c8);
        f32x4 b_hi = *(const f32x4*)(b1 + c8 + 4);
        float h[8];
        h[0] = acc[0]*0.0625f + b_lo.x; h[1] = acc[1]*0.0625f + b_lo.y;
        h[2] = acc[2]*0.0625f + b_lo.z; h[3] = acc[3]*0.0625f + b_lo.w;
        h[4] = acc[4]*0.0625f + b_hi.x; h[5] = acc[5]*0.0625f + b_hi.y;
        h[6] = acc[6]*0.0625f + b_hi.z; h[7] = acc[7]*0.0625f + b_hi.w;

        uint4_ w;
        w.x = (unsigned int)f2bf(h[0]) | ((unsigned int)f2bf(h[1]) << 16);
        w.y = (unsigned int)f2bf(h[2]) | ((unsigned int)f2bf(h[3]) << 16);
        w.z = (unsigned int)f2bf(h[4]) | ((unsigned int)f2bf(h[5]) << 16);
        w.w = (unsigned int)f2bf(h[6]) | ((unsigned int)f2bf(h[7]) << 16);
        *(uint4_*)(H1 + (size_t)row * NH + c8) = w;
    }
}

// ---------------------------------------------------------------------------
// k2 v3: out = [mean_j h_j , mean_j relu(h_j)] @ W2 + b2, with relu derived
// in-register from the gathered h rows (256 B/neighbor, half the old bytes).
// sm[r][0..127] = mean h, sm[r][128..255] = mean relu(h) — W2 layout
// matches the original concat exactly.
// ---------------------------------------------------------------------------
__global__ __launch_bounds__(256) void k2_fused(
    const unsigned short* __restrict__ H1,    // [N1, NH] bf16
    const int*   __restrict__ src1,           // [N2, FANOUT]
    const float* __restrict__ W2,             // [256, NC]
    const float* __restrict__ b2,             // [NC]
    float*       __restrict__ out)            // [N2, NC]
{
    __shared__ float sm[8][256];

    const int tid = threadIdx.x;
    const int r   = tid >> 5;                 // 0..7 (row in block)
    const int s   = tid & 31;                 // 0..31 (4-col chunk)
    const int row = blockIdx.x * 8 + r;
    const size_t c4 = (size_t)s * 4;

    float ah[4] = {0.f,0.f,0.f,0.f};          // sum h
    float ar[4] = {0.f,0.f,0.f,0.f};          // sum relu(h)
    #pragma unroll
    for (int j = 0; j < FANOUT; ++j) {
        const int nb = src1[row * FANOUT + j];
        uint2_ v = *(const uint2_*)(H1 + (size_t)nb * NH + c4);
        float e0 = bflo(v.x), e1 = bfhi(v.x), e2 = bflo(v.y), e3 = bfhi(v.y);
        ah[0] += e0; ah[1] += e1; ah[2] += e2; ah[3] += e3;
        ar[0] += e0 > 0.f ? e0 : 0.f;
        ar[1] += e1 > 0.f ? e1 : 0.f;
        ar[2] += e2 > 0.f ? e2 : 0.f;
        ar[3] += e3 > 0.f ? e3 : 0.f;
    }
    #pragma unroll
    for (int e = 0; e < 4; ++e) {
        sm[r][c4 + e]       = ah[e] * 0.0625f;
        sm[r][128 + c4 + e] = ar[e] * 0.0625f;
    }
    __syncthreads();

    const int c0 = s, c1 = s + 32;
    float o0 = b2[c0];
    float o1 = (c1 < NC) ? b2[c1] : 0.f;
    for (int k = 0; k < 256; k += 4) {
        f32x4 mv = *(const f32x4*)&sm[r][k];
        #pragma unroll
        for (int e = 0; e < 4; ++e) {
            const float* wrow = W2 + (size_t)(k + e) * NC;
            o0 += mv[e] * wrow[c0];
            if (c1 < NC) o1 += mv[e] * wrow[c1];
        }
    }
    out[(size_t)row * NC + c0] = o0;
    if (c1 < NC) out[(size_t)row * NC + c1] = o1;
}

extern "C" void kernel_launch(void* const* d_in, const int* in_sizes, int n_in,
                              void* d_out, int out_size, void* d_ws, size_t ws_size,
                              hipStream_t stream)
{
    const float* features = (const float*)d_in[0];
    const int*   src0     = (const int*)  d_in[1];
    const int*   src1     = (const int*)  d_in[2];
    const float* W1       = (const float*)d_in[3];
    const float* b1       = (const float*)d_in[4];
    const float* W2       = (const float*)d_in[5];
    const float* b2       = (const float*)d_in[6];
    float*       out      = (float*)d_out;

    unsigned short* Wt = (unsigned short*)d_ws;        // [NH][K_PAD]  = 128 KB
    unsigned short* H0 = Wt + (size_t)NH * K_PAD;      // [N0][NH] bf16 = 51.2 MB
    unsigned short* H1 = H0 + (size_t)N0 * NH;         // [N1][NH] bf16 = 6.4 MB

    hipLaunchKernelGGL(k0_transpose, dim3(K_PAD / 64), dim3(256), 0, stream, W1, Wt);
    hipLaunchKernelGGL(kA_gemm,   dim3(GRID_A),        dim3(512), 0, stream, features, Wt, H0);
    hipLaunchKernelGGL(kB_gather, dim3(N1 / 4),        dim3(256), 0, stream, H0, src0, b1, H1);
    hipLaunchKernelGGL(k2_fused,  dim3(N2 / 8),        dim3(256), 0, stream, H1, src1, W2, b2, out);
}